// Round 15
// baseline (404.068 us; speedup 1.0000x reference)
//
#include <hip/hip_runtime.h>
#include <hip/hip_bf16.h>
#include <hip/hip_cooperative_groups.h>

namespace cg = cooperative_groups;

#define NN 100000
#define NE 600000
#define HH 128
#define NB 4

typedef __attribute__((ext_vector_type(8))) short bf16x8;
typedef __attribute__((ext_vector_type(4))) float f32x4;
typedef __attribute__((ext_vector_type(4))) float vfloat4;
typedef __attribute__((ext_vector_type(4))) unsigned short ushort4v;

// round-to-nearest-even f32 -> bf16 bits (inputs are finite)
static __device__ __forceinline__ short f2bf(float f) {
  unsigned u = __float_as_uint(f);
  unsigned r = (u + 0x7fffu + ((u >> 16) & 1u)) >> 16;
  return (short)r;
}

// W8[kb][o][j] = W[o][k=kb*8+j]; k<512 -> V[k*128+o]; else loopW[(k-512)*128+o].
static __device__ __forceinline__ void build_one(const float* __restrict__ V,
                                                 const float* __restrict__ loopW,
                                                 short* __restrict__ W8, int idx)
{
  int j  = idx & 7;
  int o  = (idx >> 3) & 127;
  int kb = idx >> 10;
  int k  = kb * 8 + j;
  float v;
  if (k < 512) v = V[(size_t)k * HH + o];
  else         v = loopW[(size_t)(k - 512) * HH + o];
  W8[idx] = f2bf(v);
}

// ---- ONE cooperative kernel: prep (W8 x2, emb cast) + full CSR build ----
// 256 blocks x 1024 threads (1 block/CU, co-resident). 4 grid syncs:
//   A: deg=0, build W81/W82, cast emb->bf16   | B: degree histogram
//   C: intra-block scan of per-thread deg     | D: inter-block prefix + rowptr/cursor
//   E: scatter edges into CSR
__global__ __launch_bounds__(1024) void coop_build(
    const float* __restrict__ V1, const float* __restrict__ loop1, short* __restrict__ W81,
    const float* __restrict__ V2, const float* __restrict__ loop2, short* __restrict__ W82,
    const float* __restrict__ emb, short* __restrict__ hbf1,
    const int* __restrict__ src, const int* __restrict__ dst, const int* __restrict__ ety,
    int* __restrict__ deg, int* __restrict__ rowptr, int* __restrict__ csr,
    int* __restrict__ blocksum)
{
  cg::grid_group grid = cg::this_grid();
  __shared__ int lds[1024];
  const int tid = threadIdx.x;
  const int bid = blockIdx.x;
  const int g = bid * 1024 + tid;
  const int GT = 256 * 1024;

  // ---- phase A ----
  for (int i = g; i < NN; i += GT) deg[i] = 0;
  for (int i = g; i < 81920; i += GT) build_one(V1, loop1, W81, i);
  for (int i = g; i < 81920; i += GT) build_one(V2, loop2, W82, i);
  const int n8 = NN * HH / 8;
  for (int i = g; i < n8; i += GT) {
    const vfloat4* p = reinterpret_cast<const vfloat4*>(emb + (size_t)i * 8);
    vfloat4 a = p[0], b = p[1];
    bf16x8 o;
#pragma unroll
    for (int j = 0; j < 4; ++j) { o[j] = f2bf(a[j]); o[j + 4] = f2bf(b[j]); }
    reinterpret_cast<bf16x8*>(hbf1)[i] = o;
  }
  grid.sync();

  // ---- phase B: histogram ----
  for (int e = g; e < NE; e += GT) atomicAdd(&deg[dst[e]], 1);
  grid.sync();

  // ---- phase C: per-thread count + intra-block inclusive scan (1024) ----
  const int d = (g < NN) ? deg[g] : 0;
  lds[tid] = d;
  __syncthreads();
  for (int off = 1; off < 1024; off <<= 1) {
    int t = (tid >= off) ? lds[tid - off] : 0;
    __syncthreads();
    lds[tid] += t;
    __syncthreads();
  }
  const int myexcl = lds[tid] - d;
  if (tid == 1023) blocksum[bid] = lds[1023];
  grid.sync();

  // ---- phase D: inter-block prefix (scan 256 blocksums) + write rowptr/cursor ----
  if (tid < 256) lds[tid] = blocksum[tid];
  __syncthreads();
  for (int off = 1; off < 256; off <<= 1) {
    int t = 0;
    if (tid < 256 && tid >= off) t = lds[tid - off];
    __syncthreads();
    if (tid < 256) lds[tid] += t;
    __syncthreads();
  }
  const int preBlock = lds[bid] - blocksum[bid];
  const int run = preBlock + myexcl;
  if (g < NN) {
    rowptr[g] = run;
    deg[g] = run;                      // cursor
  } else if (g == NN) {
    rowptr[NN] = run;                  // == NE
  }
  grid.sync();

  // ---- phase E: scatter edges ----
  for (int e = g; e < NE; e += GT) {
    int dd = dst[e];
    int p = atomicAdd(&deg[dd], 1);
    csr[p] = src[e] | (ety[e] << 20);  // src:20 bits, ety:3 bits
  }
}

// ---------------- Fused layer: gather (LDS) + GEMM (unchanged from R14) ----------------
// Block = 32 nodes, 512 threads (8 waves), 48 KB LDS -> 3 blocks/CU.
// Phase 1: 4-node interleave, lane owns u32 col-pair, scalar csr/comp path.
// Phase 2: W dbuf in LDS; epilogue via LDS for coalesced full-row stores.
// NOTE: no early returns -- every thread reaches every __syncthreads.
template<int FINAL>
__global__ __launch_bounds__(512, 6) void rgcn_fused(
    const int* __restrict__ rowptr, const int* __restrict__ csr,
    const float* __restrict__ comp,   // [R,B]
    const short* __restrict__ hbf,    // [N,128] bf16
    const short* __restrict__ W8,     // [80][128][8] bf16 (slot = kb*128+o)
    const float* __restrict__ bias,   // [128]
    short* __restrict__ outH,         // [N,128] bf16 (FINAL=0)
    float* __restrict__ outF)         // [N,128] fp32 (FINAL=1)
{
  __shared__ bf16x8 gl[32][64];       // 32 KB gathered-g tile (swizzled slots)
  __shared__ bf16x8 wl[2][512];       // 16 KB W slice double-buffer

  const int tid  = threadIdx.x;
  const int wave = tid >> 6;          // 0..7
  const int lane = tid & 63;
  const int b  = lane >> 4;           // k-group g8 (gemm)
  const int q  = lane & 15;           // node r (gemm)
  const int base = blockIdx.x * 32;
  const int l4 = lane * 4;            // byte offset of this lane's u32 in h-row

  const int mt = wave >> 2;           // m-tile 0..1
  const int ct0 = (wave & 3) * 2;     // ct pair
  const int mynode = base + mt * 16 + q;

  const bf16x8* wsrc = reinterpret_cast<const bf16x8*>(W8);
  bf16x8 w0reg = wsrc[tid];

  const char* hbytes = reinterpret_cast<const char*>(hbf);
  unsigned* glu = reinterpret_cast<unsigned*>(gl);

  // ---------------- phase 1: gather (4 nodes interleaved) ----------------
  {
    const int r0 = wave * 4;
    int ii[4], EE[4];
    ii[0] = __builtin_amdgcn_readfirstlane(rowptr[base + r0]);
    EE[0] = __builtin_amdgcn_readfirstlane(rowptr[base + r0 + 1]);
    ii[1] = EE[0];
    EE[1] = __builtin_amdgcn_readfirstlane(rowptr[base + r0 + 2]);
    ii[2] = EE[1];
    EE[2] = __builtin_amdgcn_readfirstlane(rowptr[base + r0 + 3]);
    ii[3] = EE[2];
    EE[3] = __builtin_amdgcn_readfirstlane(rowptr[base + r0 + 4]);

    float acc[4][8] = {};

    while (ii[0] < EE[0] || ii[1] < EE[1] || ii[2] < EE[2] || ii[3] < EE[3]) {
      unsigned hq[16];
      int es[16];
#pragma unroll
      for (int n = 0; n < 4; ++n) {
        if (ii[n] < EE[n]) {
#pragma unroll
          for (int j = 0; j < 4; ++j) {
            const int idx = ii[n] + j;
            const int e = __builtin_amdgcn_readfirstlane(
                csr[idx < EE[n] ? idx : EE[n] - 1]);
            es[n * 4 + j] = e;
            hq[n * 4 + j] = *reinterpret_cast<const unsigned*>(
                hbytes + (((size_t)(e & 0xFFFFF)) << 8) + l4);
          }
        }
      }
#pragma unroll
      for (int n = 0; n < 4; ++n) {
        if (ii[n] < EE[n]) {
#pragma unroll
          for (int j = 0; j < 4; ++j) {
            const int idx = ii[n] + j;
            const bool v = idx < EE[n];
            const int e = es[n * 4 + j];
            const float lo = __uint_as_float(hq[n * 4 + j] << 16);
            const float hi = __uint_as_float(hq[n * 4 + j] & 0xffff0000u);
#pragma unroll
            for (int B = 0; B < 4; ++B) {
              const float c = v ? comp[(e >> 20) * NB + B] : 0.f;
              acc[n][2 * B]     += c * lo;
              acc[n][2 * B + 1] += c * hi;
            }
          }
          ii[n] += 4;
        }
      }
    }

#pragma unroll
    for (int n = 0; n < 4; ++n) {
      const int row = r0 + n;
#pragma unroll
      for (int B = 0; B < 4; ++B) {
        unsigned w = ((unsigned)(unsigned short)f2bf(acc[n][2 * B + 1]) << 16) |
                     (unsigned short)f2bf(acc[n][2 * B]);
        const int s = B * 16 + (lane >> 2);
        glu[row * 256 + ((s ^ (row & 7)) << 2) + (lane & 3)] = w;
      }
    }
  }

  // prefetch self-loop h fragments (k = 512..639): lane (q=r, b=g8)
  const bf16x8* ha = reinterpret_cast<const bf16x8*>(hbf + (size_t)mynode * HH);
  bf16x8 hreg[4];
#pragma unroll
  for (int j = 0; j < 4; ++j) hreg[j] = ha[j * 4 + b];

  wl[0][tid] = w0reg;
  __syncthreads();                    // gl + wl[0] visible

  // ---------------- phase 2: GEMM (double-buffered W slice) ----------------
  const int r  = q;
  const int g8 = b;

  f32x4 acc0 = {0.f, 0.f, 0.f, 0.f};
  f32x4 acc1 = {0.f, 0.f, 0.f, 0.f};

#pragma unroll 1
  for (int ks = 0; ks < 20; ++ks) {
    const int cur = ks & 1;
    bf16x8 nxt;
    if (ks < 19) nxt = wsrc[(ks + 1) * 512 + tid];   // issue early (T14)
    bf16x8 a = (ks < 16) ? gl[mt * 16 + r][(ks * 4 + g8) ^ (r & 7)] : hreg[ks - 16];
    bf16x8 w0 = wl[cur][g8 * 128 + (ct0 + 0) * 16 + r];
    bf16x8 w1 = wl[cur][g8 * 128 + (ct0 + 1) * 16 + r];
    acc0 = __builtin_amdgcn_mfma_f32_16x16x32_bf16(w0, a, acc0, 0, 0, 0);
    acc1 = __builtin_amdgcn_mfma_f32_16x16x32_bf16(w1, a, acc1, 0, 0, 0);
    if (ks < 19) wl[cur ^ 1][tid] = nxt;             // write late
    __syncthreads();
  }

  // ---- epilogue: stage D in LDS, then coalesced full-row writes ----
  // D mapping (verified): node = r, o = ct*16 + g8*4 + reg
  if (FINAL) {
    float* glf = reinterpret_cast<float*>(gl);
#pragma unroll
    for (int c = 0; c < 2; ++c) {
      const f32x4 acc = c ? acc1 : acc0;
      const int row = mt * 16 + r;
      const int o = (ct0 + c) * 16 + g8 * 4;
      vfloat4 bs = *reinterpret_cast<const vfloat4*>(bias + o);
      vfloat4 x;
#pragma unroll
      for (int rr = 0; rr < 4; ++rr) x[rr] = acc[rr] + bs[rr];
      const int s = (ct0 + c) * 4 + g8;
      const int phys = s ^ (row & 7);
      *reinterpret_cast<vfloat4*>(glf + row * 128 + phys * 4) = x;
    }
    __syncthreads();
#pragma unroll
    for (int p = 0; p < 2; ++p) {
      const int flat = p * 512 + tid;
      const int row = flat >> 5, s = flat & 31;
      const int phys = s ^ (row & 7);
      vfloat4 x = *reinterpret_cast<const vfloat4*>(glf + row * 128 + phys * 4);
      *reinterpret_cast<vfloat4*>(outF + (size_t)(base + row) * HH + s * 4) = x;
    }
  } else {
    short* glb = reinterpret_cast<short*>(gl);
#pragma unroll
    for (int c = 0; c < 2; ++c) {
      const f32x4 acc = c ? acc1 : acc0;
      const int row = mt * 16 + r;
      const int o = (ct0 + c) * 16 + g8 * 4;
      vfloat4 bs = *reinterpret_cast<const vfloat4*>(bias + o);
      ushort4v sv;
#pragma unroll
      for (int rr = 0; rr < 4; ++rr)
        sv[rr] = (unsigned short)f2bf(fmaxf(acc[rr] + bs[rr], 0.f));
      const int u8 = (ct0 + c) * 4 + g8;
      const int phys16 = (u8 >> 1) ^ (row & 7);
      *reinterpret_cast<ushort4v*>(glb + row * 128 + phys16 * 8 + (u8 & 1) * 4) = sv;
    }
    __syncthreads();
    {
      const int row = tid >> 4, s16 = tid & 15;
      const int phys = s16 ^ (row & 7);
      bf16x8 x = *reinterpret_cast<const bf16x8*>(glb + row * 128 + phys * 8);
      *reinterpret_cast<bf16x8*>(outH + (size_t)(base + row) * HH + s16 * 8) = x;
    }
  }
}

extern "C" void kernel_launch(void* const* d_in, const int* in_sizes, int n_in,
                              void* d_out, int out_size, void* d_ws, size_t ws_size,
                              hipStream_t stream)
{
  const int*   srcp  = (const int*)d_in[1];
  const int*   dstp  = (const int*)d_in[2];
  const int*   etp   = (const int*)d_in[3];
  const float* emb   = (const float*)d_in[4];
  const float* V1    = (const float*)d_in[5];
  const float* comp1 = (const float*)d_in[6];
  const float* loop1 = (const float*)d_in[7];
  const float* bias1 = (const float*)d_in[8];
  const float* V2    = (const float*)d_in[9];
  const float* comp2 = (const float*)d_in[10];
  const float* loop2 = (const float*)d_in[11];
  const float* bias2 = (const float*)d_in[12];
  float* out = (float*)d_out;

  char* ws = (char*)d_ws;
  short* Wt1      = (short*)(ws);                        // 163,840 B
  short* Wt2      = (short*)(ws + 163840);               // 163,840 B
  short* hbf1     = (short*)(ws + 327680);               // 25,600,000 B
  short* hbf2     = (short*)(ws + 25927680);             // 25,600,000 B
  int*   deg      = (int*)  (ws + 51527680);             // 400,000 B (doubles as cursor)
  int*   rowptr   = (int*)  (ws + 51927680);             // 400,004 B
  int*   csr      = (int*)  (ws + 52327696);             // 2,400,000 B
  int*   blocksum = (int*)  (ws + 54727696);             // 1,024 B  (total ~54.7 MB)

  const int fused_blocks = NN / 32;                      // 3125 (NN % 32 == 0)

  // --- one cooperative dispatch: prep + CSR build ---
  void* cargs[] = {
    (void*)&V1, (void*)&loop1, (void*)&Wt1,
    (void*)&V2, (void*)&loop2, (void*)&Wt2,
    (void*)&emb, (void*)&hbf1,
    (void*)&srcp, (void*)&dstp, (void*)&etp,
    (void*)&deg, (void*)&rowptr, (void*)&csr, (void*)&blocksum
  };
  hipLaunchCooperativeKernel((void*)coop_build, dim3(256), dim3(1024),
                             cargs, 0, stream);

  // Layer 1 (fused gather+GEMM, bf16 relu output)
  hipLaunchKernelGGL((rgcn_fused<0>), dim3(fused_blocks), dim3(512), 0, stream,
                     rowptr, csr, comp1, hbf1, Wt1, bias1, hbf2, (float*)nullptr);

  // Layer 2 (fused, fp32 output)
  hipLaunchKernelGGL((rgcn_fused<1>), dim3(fused_blocks), dim3(512), 0, stream,
                     rowptr, csr, comp2, hbf2, Wt2, bias2, (short*)nullptr, out);
}

// Round 16
// 288.535 us; speedup vs baseline: 1.4004x; 1.4004x over previous
//
#include <hip/hip_runtime.h>
#include <hip/hip_bf16.h>

#define NN 100000
#define NE 600000
#define HH 128
#define NB 4
#define TILE 2048
#define NTILES ((NN + TILE - 1) / TILE)   // 49

typedef __attribute__((ext_vector_type(8))) short bf16x8;
typedef __attribute__((ext_vector_type(4))) float f32x4;
typedef __attribute__((ext_vector_type(4))) float vfloat4;
typedef __attribute__((ext_vector_type(4))) unsigned short ushort4v;

// round-to-nearest-even f32 -> bf16 bits (inputs are finite)
static __device__ __forceinline__ short f2bf(float f) {
  unsigned u = __float_as_uint(f);
  unsigned r = (u + 0x7fffu + ((u >> 16) & 1u)) >> 16;
  return (short)r;
}

// ---- fused prep: W8 both layers + emb->bf16 cast + degree histogram ----
// W8[kb][o][j] = W[o][k=kb*8+j]; k<512 -> V[k*128+o]; else loopW[(k-512)*128+o].
static __device__ __forceinline__ void build_one(const float* __restrict__ V,
                                                 const float* __restrict__ loopW,
                                                 short* __restrict__ W8, int idx)
{
  int j  = idx & 7;
  int o  = (idx >> 3) & 127;
  int kb = idx >> 10;
  int k  = kb * 8 + j;
  float v;
  if (k < 512) v = V[(size_t)k * HH + o];
  else         v = loopW[(size_t)(k - 512) * HH + o];
  W8[idx] = f2bf(v);
}

__global__ __launch_bounds__(256) void prep_all(
    const float* __restrict__ V1, const float* __restrict__ loop1, short* __restrict__ W81,
    const float* __restrict__ V2, const float* __restrict__ loop2, short* __restrict__ W82,
    const float* __restrict__ emb, short* __restrict__ hbf1,
    const int* __restrict__ dst, int* __restrict__ deg)
{
  const int bid = blockIdx.x;
  if (bid < 320) {
    build_one(V1, loop1, W81, bid * 256 + threadIdx.x);
  } else if (bid < 640) {
    build_one(V2, loop2, W82, (bid - 320) * 256 + threadIdx.x);
  } else if (bid < 2984) {                    // degree histogram (2344 blocks)
    int e = (bid - 640) * 256 + threadIdx.x;
    if (e < NE) atomicAdd(&deg[dst[e]], 1);
  } else {                                    // emb -> bf16 (800 blocks)
    const int n8 = NN * HH / 8;               // 1,600,000
    int i = (bid - 2984) * 256 + threadIdx.x;
    for (; i < n8; i += 800 * 256) {
      const vfloat4* p = reinterpret_cast<const vfloat4*>(emb + (size_t)i * 8);
      vfloat4 a = p[0], b = p[1];
      bf16x8 o;
#pragma unroll
      for (int j = 0; j < 4; ++j) { o[j] = f2bf(a[j]); o[j + 4] = f2bf(b[j]); }
      reinterpret_cast<bf16x8*>(hbf1)[i] = o;
    }
  }
}

// ---------------- CSR build ----------------

__global__ __launch_bounds__(256) void scan_tiles(const int* __restrict__ deg,
                                                  int* __restrict__ tilesum)
{
  __shared__ int red[256];
  const int tid = threadIdx.x;
  int base = blockIdx.x * TILE + tid * 8;
  int s = 0;
#pragma unroll
  for (int j = 0; j < 8; ++j) {
    int i = base + j;
    if (i < NN) s += deg[i];
  }
  red[tid] = s;
  __syncthreads();
  for (int off = 128; off > 0; off >>= 1) {
    if (tid < off) red[tid] += red[tid + off];
    __syncthreads();
  }
  if (tid == 0) tilesum[blockIdx.x] = red[0];
}

__global__ __launch_bounds__(256) void scan_final(const int* deg,
                                                  const int* __restrict__ tilesum,
                                                  int* __restrict__ rowptr,
                                                  int* cursor)
{
  __shared__ int lds[256];
  const int tid = threadIdx.x;
  int pre = 0;
  for (int t = 0; t < NTILES; ++t)
    if (t < blockIdx.x) pre += tilesum[t];

  int base = blockIdx.x * TILE + tid * 8;
  int d[8];
  int s = 0;
#pragma unroll
  for (int j = 0; j < 8; ++j) {
    int i = base + j;
    d[j] = (i < NN) ? deg[i] : 0;
    s += d[j];
  }
  lds[tid] = s;
  __syncthreads();
  for (int off = 1; off < 256; off <<= 1) {
    int t = (tid >= off) ? lds[tid - off] : 0;
    __syncthreads();
    lds[tid] += t;
    __syncthreads();
  }
  int run = pre + lds[tid] - s;
#pragma unroll
  for (int j = 0; j < 8; ++j) {
    int i = base + j;
    if (i < NN) {
      rowptr[i] = run;
      cursor[i] = run;
      run += d[j];
    }
  }
  if (blockIdx.x == NTILES - 1 && tid == 255)
    rowptr[NN] = pre + lds[255];
}

__global__ __launch_bounds__(256) void scatter_edges(
    const int* __restrict__ src, const int* __restrict__ dst, const int* __restrict__ ety,
    int* __restrict__ cursor, int* __restrict__ csr)
{
  int e = blockIdx.x * blockDim.x + threadIdx.x;
  if (e >= NE) return;
  int d = dst[e];
  int p = atomicAdd(&cursor[d], 1);
  csr[p] = src[e] | (ety[e] << 20);            // src:20 bits, ety:3 bits
}

// ---------------- Fused layer: gather (LDS) + GEMM ----------------
// Block = 32 nodes, 512 threads (8 waves), 48 KB LDS -> 3 blocks/CU.
// Phase 1: 4-NODE INTERLEAVE -- all 16 row-loads (4 nodes x masked quad)
// issued before any FMA consumes them. Lane l owns u32 col-pair {2l,2l+1};
// csr/comp stay on the scalar path.
// Phase 2: wave w -> m-tile (w>>2), ct pair (w&3)*2+{0,1}; W dbuf in LDS.
// Epilogue: D staged in gl (dead after last K-step), coalesced full rows out.
// NOTE: no early returns -- every thread reaches every __syncthreads.
template<int FINAL>
__global__ __launch_bounds__(512, 6) void rgcn_fused(
    const int* __restrict__ rowptr, const int* __restrict__ csr,
    const float* __restrict__ comp,   // [R,B]
    const short* __restrict__ hbf,    // [N,128] bf16
    const short* __restrict__ W8,     // [80][128][8] bf16 (slot = kb*128+o)
    const float* __restrict__ bias,   // [128]
    short* __restrict__ outH,         // [N,128] bf16 (FINAL=0)
    float* __restrict__ outF)         // [N,128] fp32 (FINAL=1)
{
  __shared__ bf16x8 gl[32][64];       // 32 KB gathered-g tile (swizzled slots)
  __shared__ bf16x8 wl[2][512];       // 16 KB W slice double-buffer

  const int tid  = threadIdx.x;
  const int wave = tid >> 6;          // 0..7
  const int lane = tid & 63;
  const int b  = lane >> 4;           // k-group g8 (gemm)
  const int q  = lane & 15;           // node r (gemm)
  const int base = blockIdx.x * 32;
  const int l4 = lane * 4;            // byte offset of this lane's u32 in h-row

  const int mt = wave >> 2;           // m-tile 0..1
  const int ct0 = (wave & 3) * 2;     // ct pair
  const int mynode = base + mt * 16 + q;

  const bf16x8* wsrc = reinterpret_cast<const bf16x8*>(W8);
  bf16x8 w0reg = wsrc[tid];

  const char* hbytes = reinterpret_cast<const char*>(hbf);
  unsigned* glu = reinterpret_cast<unsigned*>(gl);

  // ---------------- phase 1: gather (4 nodes interleaved) ----------------
  {
    const int r0 = wave * 4;
    int ii[4], EE[4];
    ii[0] = __builtin_amdgcn_readfirstlane(rowptr[base + r0]);
    EE[0] = __builtin_amdgcn_readfirstlane(rowptr[base + r0 + 1]);
    ii[1] = EE[0];
    EE[1] = __builtin_amdgcn_readfirstlane(rowptr[base + r0 + 2]);
    ii[2] = EE[1];
    EE[2] = __builtin_amdgcn_readfirstlane(rowptr[base + r0 + 3]);
    ii[3] = EE[2];
    EE[3] = __builtin_amdgcn_readfirstlane(rowptr[base + r0 + 4]);

    float acc[4][8] = {};

    while (ii[0] < EE[0] || ii[1] < EE[1] || ii[2] < EE[2] || ii[3] < EE[3]) {
      unsigned hq[16];
      int es[16];
      // ---- issue phase: up to 16 independent row loads ----
#pragma unroll
      for (int n = 0; n < 4; ++n) {
        if (ii[n] < EE[n]) {
#pragma unroll
          for (int j = 0; j < 4; ++j) {
            const int idx = ii[n] + j;
            const int e = __builtin_amdgcn_readfirstlane(
                csr[idx < EE[n] ? idx : EE[n] - 1]);
            es[n * 4 + j] = e;
            hq[n * 4 + j] = *reinterpret_cast<const unsigned*>(
                hbytes + (((size_t)(e & 0xFFFFF)) << 8) + l4);
          }
        }
      }
      // ---- consume phase ----
#pragma unroll
      for (int n = 0; n < 4; ++n) {
        if (ii[n] < EE[n]) {
#pragma unroll
          for (int j = 0; j < 4; ++j) {
            const int idx = ii[n] + j;
            const bool v = idx < EE[n];
            const int e = es[n * 4 + j];
            const float lo = __uint_as_float(hq[n * 4 + j] << 16);
            const float hi = __uint_as_float(hq[n * 4 + j] & 0xffff0000u);
#pragma unroll
            for (int B = 0; B < 4; ++B) {
              const float c = v ? comp[(e >> 20) * NB + B] : 0.f;
              acc[n][2 * B]     += c * lo;
              acc[n][2 * B + 1] += c * hi;
            }
          }
          ii[n] += 4;
        }
      }
    }

    // pack 2 bf16 per u32, 4 u32 per node (swizzled slots)
#pragma unroll
    for (int n = 0; n < 4; ++n) {
      const int row = r0 + n;
#pragma unroll
      for (int B = 0; B < 4; ++B) {
        unsigned w = ((unsigned)(unsigned short)f2bf(acc[n][2 * B + 1]) << 16) |
                     (unsigned short)f2bf(acc[n][2 * B]);
        const int s = B * 16 + (lane >> 2);
        glu[row * 256 + ((s ^ (row & 7)) << 2) + (lane & 3)] = w;
      }
    }
  }

  // prefetch self-loop h fragments (k = 512..639): lane (q=r, b=g8)
  const bf16x8* ha = reinterpret_cast<const bf16x8*>(hbf + (size_t)mynode * HH);
  bf16x8 hreg[4];
#pragma unroll
  for (int j = 0; j < 4; ++j) hreg[j] = ha[j * 4 + b];

  // stage W slice 0 (reg was loaded before gather)
  wl[0][tid] = w0reg;
  __syncthreads();                    // gl + wl[0] visible

  // ---------------- phase 2: GEMM (double-buffered W slice) ----------------
  const int r  = q;
  const int g8 = b;

  f32x4 acc0 = {0.f, 0.f, 0.f, 0.f};
  f32x4 acc1 = {0.f, 0.f, 0.f, 0.f};

#pragma unroll 1
  for (int ks = 0; ks < 20; ++ks) {
    const int cur = ks & 1;
    bf16x8 nxt;
    if (ks < 19) nxt = wsrc[(ks + 1) * 512 + tid];   // issue early (T14)
    // A fragment: k = ks*32 + g8*8 + j ; logical slot = ks*4+g8
    bf16x8 a = (ks < 16) ? gl[mt * 16 + r][(ks * 4 + g8) ^ (r & 7)] : hreg[ks - 16];
    bf16x8 w0 = wl[cur][g8 * 128 + (ct0 + 0) * 16 + r];
    bf16x8 w1 = wl[cur][g8 * 128 + (ct0 + 1) * 16 + r];
    acc0 = __builtin_amdgcn_mfma_f32_16x16x32_bf16(w0, a, acc0, 0, 0, 0);
    acc1 = __builtin_amdgcn_mfma_f32_16x16x32_bf16(w1, a, acc1, 0, 0, 0);
    if (ks < 19) wl[cur ^ 1][tid] = nxt;             // write late
    __syncthreads();
  }

  // ---- epilogue: stage D in LDS, then coalesced full-row writes ----
  // D mapping (verified): node = r, o = ct*16 + g8*4 + reg
  if (FINAL) {
    float* glf = reinterpret_cast<float*>(gl);       // [32 rows][128 f32] swizzled
#pragma unroll
    for (int c = 0; c < 2; ++c) {
      const f32x4 acc = c ? acc1 : acc0;
      const int row = mt * 16 + r;
      const int o = (ct0 + c) * 16 + g8 * 4;
      vfloat4 bs = *reinterpret_cast<const vfloat4*>(bias + o);
      vfloat4 x;
#pragma unroll
      for (int rr = 0; rr < 4; ++rr) x[rr] = acc[rr] + bs[rr];
      const int s = (ct0 + c) * 4 + g8;              // 16B slot in row (0..31)
      const int phys = s ^ (row & 7);
      *reinterpret_cast<vfloat4*>(glf + row * 128 + phys * 4) = x;
    }
    __syncthreads();
#pragma unroll
    for (int p = 0; p < 2; ++p) {
      const int flat = p * 512 + tid;                // 1024 slots of 16B
      const int row = flat >> 5, s = flat & 31;
      const int phys = s ^ (row & 7);
      vfloat4 x = *reinterpret_cast<const vfloat4*>(glf + row * 128 + phys * 4);
      *reinterpret_cast<vfloat4*>(outF + (size_t)(base + row) * HH + s * 4) = x;
    }
  } else {
    short* glb = reinterpret_cast<short*>(gl);       // [32 rows][128 bf16] swizzled
#pragma unroll
    for (int c = 0; c < 2; ++c) {
      const f32x4 acc = c ? acc1 : acc0;
      const int row = mt * 16 + r;
      const int o = (ct0 + c) * 16 + g8 * 4;
      vfloat4 bs = *reinterpret_cast<const vfloat4*>(bias + o);
      ushort4v sv;
#pragma unroll
      for (int rr = 0; rr < 4; ++rr)
        sv[rr] = (unsigned short)f2bf(fmaxf(acc[rr] + bs[rr], 0.f));
      const int u8 = (ct0 + c) * 4 + g8;             // 8B unit in row (0..31)
      const int phys16 = (u8 >> 1) ^ (row & 7);      // swizzle at 16B granularity
      *reinterpret_cast<ushort4v*>(glb + row * 128 + phys16 * 8 + (u8 & 1) * 4) = sv;
    }
    __syncthreads();
    {
      const int row = tid >> 4, s16 = tid & 15;      // 512 slots of 16B
      const int phys = s16 ^ (row & 7);
      bf16x8 x = *reinterpret_cast<const bf16x8*>(glb + row * 128 + phys * 8);
      *reinterpret_cast<bf16x8*>(outH + (size_t)(base + row) * HH + s16 * 8) = x;
    }
  }
}

extern "C" void kernel_launch(void* const* d_in, const int* in_sizes, int n_in,
                              void* d_out, int out_size, void* d_ws, size_t ws_size,
                              hipStream_t stream)
{
  const int*   srcp  = (const int*)d_in[1];
  const int*   dstp  = (const int*)d_in[2];
  const int*   etp   = (const int*)d_in[3];
  const float* emb   = (const float*)d_in[4];
  const float* V1    = (const float*)d_in[5];
  const float* comp1 = (const float*)d_in[6];
  const float* loop1 = (const float*)d_in[7];
  const float* bias1 = (const float*)d_in[8];
  const float* V2    = (const float*)d_in[9];
  const float* comp2 = (const float*)d_in[10];
  const float* loop2 = (const float*)d_in[11];
  const float* bias2 = (const float*)d_in[12];
  float* out = (float*)d_out;

  char* ws = (char*)d_ws;
  short* Wt1     = (short*)(ws);                         // 163,840 B
  short* Wt2     = (short*)(ws + 163840);                // 163,840 B
  short* hbf1    = (short*)(ws + 327680);                // 25,600,000 B
  short* hbf2    = (short*)(ws + 25927680);              // 25,600,000 B
  int*   deg     = (int*)  (ws + 51527680);              // 400,000 B (doubles as cursor)
  int*   rowptr  = (int*)  (ws + 51927680);              // 400,004 B
  int*   csr     = (int*)  (ws + 52327696);              // 2,400,000 B
  int*   tilesum = (int*)  (ws + 54727696);              // 196 B  (total ~54.7 MB)

  const int fused_blocks = NN / 32;                      // 3125 (NN % 32 == 0)
  const int e_blocks     = (NE + 255) / 256;

  hipMemsetAsync(deg, 0, NN * sizeof(int), stream);

  // fused prep: W8 both layers + bf16 cast + degree histogram (1 dispatch)
  hipLaunchKernelGGL(prep_all, dim3(3784), dim3(256), 0, stream,
                     V1, loop1, Wt1, V2, loop2, Wt2, emb, hbf1, dstp, deg);

  hipLaunchKernelGGL(scan_tiles, dim3(NTILES), dim3(256), 0, stream, deg, tilesum);
  hipLaunchKernelGGL(scan_final, dim3(NTILES), dim3(256), 0, stream,
                     deg, tilesum, rowptr, deg);
  hipLaunchKernelGGL(scatter_edges, dim3(e_blocks), dim3(256), 0, stream,
                     srcp, dstp, etp, deg, csr);

  // Layer 1 (fused gather+GEMM, bf16 relu output)
  hipLaunchKernelGGL((rgcn_fused<0>), dim3(fused_blocks), dim3(512), 0, stream,
                     rowptr, csr, comp1, hbf1, Wt1, bias1, hbf2, (float*)nullptr);

  // Layer 2 (fused, fp32 output)
  hipLaunchKernelGGL((rgcn_fused<1>), dim3(fused_blocks), dim3(512), 0, stream,
                     rowptr, csr, comp2, hbf2, Wt2, bias2, (short*)nullptr, out);
}